// Round 1
// baseline (383.968 us; speedup 1.0000x reference)
//
#include <hip/hip_runtime.h>

// out[b,i,o] = S[b,i,:]·W[o,:] + A[b,i]*bias[o]
//   S[b,i,d] = sum_j adj[b,i,j] * (text[b,j,d] + dep_embed[b,j,i,d])
//   A[b,i]   = sum_j adj[b,i,j]
// B=4, L=256, D_IN=D_OUT=256. Memory-bound on dep_embed (268 MB fp32).

#define LL 256
#define DD 256
#define D4 64   // DD/4

__global__ __launch_bounds__(256) void tgc_fused_kernel(
    const float* __restrict__ text,     // [B,L,D]
    const float* __restrict__ adj,      // [B,L,L]
    const float* __restrict__ dep,      // [B,L,L,D]
    const float* __restrict__ W,        // [Do,Di] row-major
    const float* __restrict__ bias,     // [Do]
    float* __restrict__ out)            // [B,L,Do]
{
    const int bi = blockIdx.x;          // b*L + i
    const int b  = bi >> 8;
    const int i  = bi & 255;
    const int t  = threadIdx.x;
    const int g  = t >> 6;              // j-group 0..3
    const int l  = t & 63;              // lane within group; covers d = 4l..4l+3

    __shared__ float  adjs[LL];
    __shared__ float4 red[4][64];
    __shared__ float  ared[4];
    __shared__ float4 sfin[64];

    // stage adj row (coalesced), then broadcast-read from LDS
    adjs[t] = adj[bi * LL + t];
    __syncthreads();

    const float4* text4 = (const float4*)text;
    const float4* dep4  = (const float4*)dep;

    float4 acc = make_float4(0.f, 0.f, 0.f, 0.f);
    float  asum = 0.f;

    // group g handles j = 4*jj + g; dep slice [b,j,i,:] is 1KB contiguous,
    // 64 lanes x float4 = one fully-coalesced 1KB wave read
    #pragma unroll 8
    for (int jj = 0; jj < 64; ++jj) {
        const int j = (jj << 2) + g;
        const float a  = adjs[j];
        const float4 tv = text4[(b * LL + j) * D4 + l];          // L2-resident re-read
        const float4 dv = dep4[((b * LL + j) * LL + i) * D4 + l]; // the HBM stream
        acc.x += a * (tv.x + dv.x);
        acc.y += a * (tv.y + dv.y);
        acc.z += a * (tv.z + dv.z);
        acc.w += a * (tv.w + dv.w);
        asum  += a;   // same value across lanes of a group
    }

    red[g][l] = acc;
    if (l == 0) ared[g] = asum;
    __syncthreads();

    if (g == 0) {
        const float4 r0 = red[0][l], r1 = red[1][l], r2 = red[2][l], r3 = red[3][l];
        float4 s;
        s.x = r0.x + r1.x + r2.x + r3.x;
        s.y = r0.y + r1.y + r2.y + r3.y;
        s.z = r0.z + r1.z + r2.z + r3.z;
        s.w = r0.w + r1.w + r2.w + r3.w;
        sfin[l] = s;
    }
    __syncthreads();

    const float A = ared[0] + ared[1] + ared[2] + ared[3];

    // epilogue: thread t = output column o. W row streamed per-lane (L1/L2-
    // cached, W is only 256KB total); sfin reads are same-address broadcasts.
    const float4* W4 = (const float4*)W;
    float oacc = 0.f;
    #pragma unroll 8
    for (int d4 = 0; d4 < D4; ++d4) {
        const float4 s = sfin[d4];
        const float4 w = W4[t * D4 + d4];
        oacc += s.x * w.x + s.y * w.y + s.z * w.z + s.w * w.w;
    }
    out[bi * DD + t] = oacc + A * bias[t];
}

extern "C" void kernel_launch(void* const* d_in, const int* in_sizes, int n_in,
                              void* d_out, int out_size, void* d_ws, size_t ws_size,
                              hipStream_t stream) {
    const float* text = (const float*)d_in[0];
    const float* adj  = (const float*)d_in[1];
    const float* dep  = (const float*)d_in[2];
    const float* W    = (const float*)d_in[3];
    const float* bias = (const float*)d_in[4];
    float* out = (float*)d_out;

    // one block per (b,i): 4*256 = 1024 blocks
    tgc_fused_kernel<<<dim3(1024), dim3(256), 0, stream>>>(text, adj, dep, W, bias, out);
}